// Round 1
// baseline (395.004 us; speedup 1.0000x reference)
//
#include <hip/hip_runtime.h>
#include <math.h>

#define N_NODES 50000
#define N_EDGES 1600000
#define D_IN 128
#define D_OUT 32
#define ALPHA 0.2f

// Monotone float<->int key (involution). Works with signed atomicMin/Max.
__device__ __forceinline__ int enc_f(float x) {
    int i = __float_as_int(x);
    return i >= 0 ? i : (i ^ 0x7fffffff);
}
__device__ __forceinline__ float dec_f(int k) {
    return __int_as_float(k >= 0 ? k : (k ^ 0x7fffffff));
}

// Kernel A: X_prime = X @ W  [N,32], s0 = Xp.a0, s1 = Xp.a1.
// 8 nodes per 256-thread block; 32 lanes per node (one per output dim).
// Also initializes the min/max atomic slots (safe: stream-ordered before B).
__global__ __launch_bounds__(256) void k_xw(const float* __restrict__ X,
                                            const float* __restrict__ W,
                                            const float* __restrict__ a0,
                                            const float* __restrict__ a1,
                                            float* __restrict__ Xp,
                                            float* __restrict__ s0,
                                            float* __restrict__ s1,
                                            int* __restrict__ minmax) {
    __shared__ float Wl[D_IN * D_OUT]; // 16 KiB
    __shared__ float Xl[8 * D_IN];     // 4 KiB
    const int tid = threadIdx.x;
    if (blockIdx.x == 0 && tid == 0) {
        minmax[0] = 0x7fffffff; // running min key
        minmax[1] = 0x80000000; // running max key
    }
    for (int i = tid; i < D_IN * D_OUT; i += 256) Wl[i] = W[i];
    const int node0 = blockIdx.x * 8; // 50000/8 = 6250 blocks, no tail
    for (int i = tid; i < 8 * D_IN; i += 256) Xl[i] = X[(size_t)node0 * D_IN + i];
    __syncthreads();

    const int g = tid >> 5;   // node group within block
    const int t = tid & 31;   // output dim
    const int node = node0 + g;
    const float* xr = &Xl[g * D_IN];
    float acc = 0.f;
#pragma unroll
    for (int k = 0; k < D_IN; ++k) acc += xr[k] * Wl[k * D_OUT + t];
    Xp[(size_t)node * D_OUT + t] = acc;

    float v0 = acc * a0[t];
    float v1 = acc * a1[t];
#pragma unroll
    for (int m = 16; m >= 1; m >>= 1) {
        v0 += __shfl_xor(v0, m);
        v1 += __shfl_xor(v1, m);
    }
    if (t == 0) { s0[node] = v0; s1[node] = v1; }
}

// Kernel B: global min/max of leakyrelu(s0[row]+s1[col]) over all edges.
__global__ __launch_bounds__(256) void k_minmax(const int* __restrict__ row,
                                                const int* __restrict__ col,
                                                const float* __restrict__ s0,
                                                const float* __restrict__ s1,
                                                int* __restrict__ minmax) {
    const int tid = blockIdx.x * blockDim.x + threadIdx.x;
    const int stride = gridDim.x * blockDim.x;
    int kmin = 0x7fffffff, kmax = 0x80000000;
    for (int e = tid; e < N_EDGES; e += stride) {
        float a = s0[row[e]] + s1[col[e]];
        a = a > 0.f ? a : ALPHA * a;
        int k = enc_f(a);
        kmin = min(kmin, k);
        kmax = max(kmax, k);
    }
#pragma unroll
    for (int m = 32; m >= 1; m >>= 1) {
        kmin = min(kmin, __shfl_xor(kmin, m));
        kmax = max(kmax, __shfl_xor(kmax, m));
    }
    __shared__ int smn[4], smx[4];
    const int wave = threadIdx.x >> 6;
    if ((threadIdx.x & 63) == 0) { smn[wave] = kmin; smx[wave] = kmax; }
    __syncthreads();
    if (threadIdx.x == 0) {
#pragma unroll
        for (int w = 1; w < 4; ++w) { kmin = min(kmin, smn[w]); kmax = max(kmax, smx[w]); }
        atomicMin(&minmax[0], kmin);
        atomicMax(&minmax[1], kmax);
    }
}

// Kernel C: per edge: w = exp(minmaxnorm(leakyrelu(att))); scatter-add
// w * Xp[col] into out[row], and w into rows_sum[row].
// 32 lanes per edge -> coalesced gather + coalesced atomics per edge.
__global__ __launch_bounds__(256) void k_scatter(const int* __restrict__ row,
                                                 const int* __restrict__ col,
                                                 const float* __restrict__ s0,
                                                 const float* __restrict__ s1,
                                                 const float* __restrict__ Xp,
                                                 const int* __restrict__ minmax,
                                                 float* __restrict__ out,
                                                 float* __restrict__ rows_sum) {
    const long long gid = (long long)blockIdx.x * 256 + threadIdx.x;
    const int e = (int)(gid >> 5);
    const int d = (int)(gid & 31);
    if (e >= N_EDGES) return;
    const int r = row[e];
    const int c = col[e];
    float a = s0[r] + s1[c];
    a = a > 0.f ? a : ALPHA * a;
    const float mn = dec_f(minmax[0]);
    const float mx = dec_f(minmax[1]);
    const float w = __expf((a - mn) / (mx - mn));
    atomicAdd(&out[(size_t)r * D_OUT + d], w * Xp[(size_t)c * D_OUT + d]);
    if (d == 0) atomicAdd(&rows_sum[r], w);
}

// Kernel D: out /= rows_sum (broadcast per row)
__global__ __launch_bounds__(256) void k_div(float* __restrict__ out,
                                             const float* __restrict__ rows_sum) {
    const int i = blockIdx.x * 256 + threadIdx.x;
    if (i >= N_NODES * D_OUT) return;
    out[i] = out[i] / rows_sum[i >> 5];
}

extern "C" void kernel_launch(void* const* d_in, const int* in_sizes, int n_in,
                              void* d_out, int out_size, void* d_ws, size_t ws_size,
                              hipStream_t stream) {
    const float* X  = (const float*)d_in[0];
    const float* W  = (const float*)d_in[1];
    const float* a0 = (const float*)d_in[2];
    const float* a1 = (const float*)d_in[3];
    const int* row  = (const int*)d_in[4];
    const int* col  = (const int*)d_in[5];
    float* out = (float*)d_out;

    // Workspace layout (floats): [minmax(2 ints) pad to 64][rows_sum][s0][s1][Xp]
    float* ws = (float*)d_ws;
    int*   minmax   = (int*)ws;
    float* rows_sum = ws + 64;
    float* s0 = rows_sum + 50048;
    float* s1 = s0 + 50048;
    float* Xp = s1 + 50048;

    hipMemsetAsync(d_out, 0, (size_t)N_NODES * D_OUT * sizeof(float), stream);
    hipMemsetAsync(rows_sum, 0, (size_t)N_NODES * sizeof(float), stream);

    k_xw<<<N_NODES / 8, 256, 0, stream>>>(X, W, a0, a1, Xp, s0, s1, minmax);
    k_minmax<<<1024, 256, 0, stream>>>(row, col, s0, s1, minmax);
    k_scatter<<<((long long)N_EDGES * 32 + 255) / 256, 256, 0, stream>>>(
        row, col, s0, s1, Xp, minmax, out, rows_sum);
    k_div<<<(N_NODES * D_OUT + 255) / 256, 256, 0, stream>>>(out, rows_sum);
}